// Round 17
// baseline (435.533 us; speedup 1.0000x reference)
//
#include <hip/hip_runtime.h>
#include <hip/hip_fp16.h>

// Pipeline (all fp16 MFMA, f32 accum), R7-proven 3-stage GEMM structure:
//   Algebraic fusion (R10): q·k^T = b(Wq^T Wk)e^T + b·w1 + (e·w2) + c0.
//   Merged projection (R11): S_big = b_h @ [Mt|w1|0|Wv]^T + bias  [BT,1408]
//     cols 0..799 = bm' (attn A), cols 800..1407 = v (out B).
//   attn = tanh(NT(S_big[,0:800], e'))  batched ; out = NT(attn, S_big[,800:]).
// R17: gemm256m -> 4 FAT waves of 64x128 (acc[4][8], 12 ds_read per 32 MFMA
//   vs 8 per 16) -- relieves the LDS-read pipe (per-CU/step 1536->1152 cyc,
//   now < MFMA 1280 cyc). 256 threads, 6 loads/thread/stage -> vmcnt(6).
//   LDS still 72 KB -> 2 blocks/CU. Same 3-stage counted-vmcnt skeleton.
// R15: fast tanh epilogue: tanh(x) = 1 - 2*rcp(exp2(2log2e*x)+1).
// XOR-swizzled LDS slots (verified R6): chunk c -> row c>>2, col
// ((c&3)^((c>>3)&3))*8; read lane l row r: chunk r*4 + ((l>>4)^((r>>1)&3)).
// 0 bank conflicts + intact 64B-line write coalescing.
// MODE0 = bijective XCD chunking; MODE1 = batch->XCD co-location.
// NOTE (R8/R12/R13/R14): K=768 too shallow for 8-phase/256^2-BK64 schedules;
// occupancy-rich 3-stage is the right structure here.

typedef _Float16 f16x8 __attribute__((ext_vector_type(8)));
typedef _Float16 f16x4 __attribute__((ext_vector_type(4)));
typedef float f32x4 __attribute__((ext_vector_type(4)));

__global__ void cvt8_kernel(const float* __restrict__ src, _Float16* __restrict__ dst,
                            long long n8) {
    long long i = blockIdx.x * (long long)blockDim.x + threadIdx.x;
    const long long stride = gridDim.x * (long long)blockDim.x;
    for (; i < n8; i += stride) {
        const float4 f0 = ((const float4*)src)[2 * i];
        const float4 f1 = ((const float4*)src)[2 * i + 1];
        f16x8 h;
        h[0] = (_Float16)f0.x; h[1] = (_Float16)f0.y; h[2] = (_Float16)f0.z; h[3] = (_Float16)f0.w;
        h[4] = (_Float16)f1.x; h[5] = (_Float16)f1.y; h[6] = (_Float16)f1.z; h[7] = (_Float16)f1.w;
        ((f16x8*)dst)[i] = h;
    }
}

// two f32 [768,768] -> f16 transposed [768,768] (z selects matrix)
__global__ void cvtT2_kernel(const float* __restrict__ s0, _Float16* __restrict__ d0,
                             const float* __restrict__ s1, _Float16* __restrict__ d1) {
    __shared__ float t[32][33];
    const float* src = blockIdx.z ? s1 : s0;
    _Float16* dst = blockIdx.z ? d1 : d0;
    const int bx = blockIdx.x, by = blockIdx.y;
    const int tx = threadIdx.x & 31, ty = threadIdx.x >> 5;
#pragma unroll
    for (int k = 0; k < 4; ++k) {
        const int r = ty + 8 * k;
        t[r][tx] = src[(size_t)(by * 32 + r) * 768 + bx * 32 + tx];
    }
    __syncthreads();
#pragma unroll
    for (int k = 0; k < 4; ++k) {
        const int r = ty + 8 * k;
        dst[(size_t)(bx * 32 + r) * 768 + by * 32 + tx] = (_Float16)t[tx][r];
    }
}

// w1 -> Mt_aug row 768 ; w2f ; bias_mg[1408] ; zero Mt_aug rows 769..799
__global__ void prep_kernel(const _Float16* __restrict__ WqT, const _Float16* __restrict__ WkT,
                            const float* __restrict__ bq, const float* __restrict__ bk,
                            const float* __restrict__ bv,
                            float* __restrict__ w2f, _Float16* __restrict__ Mt_aug,
                            float* __restrict__ bias_mg) {
    const int wid = blockIdx.x * 4 + (threadIdx.x >> 6);
    const int lane = threadIdx.x & 63;
    if (wid < 768) {                 // w1[wid] = WqT[wid,:]·bk
        float s = 0.f;
        for (int k = 0; k < 12; ++k) s += (float)WqT[(size_t)wid * 768 + lane + 64 * k] * bk[lane + 64 * k];
        for (int o = 32; o; o >>= 1) s += __shfl_xor(s, o);
        if (lane == 0) Mt_aug[(size_t)768 * 768 + wid] = (_Float16)s;
    } else if (wid < 1536) {         // w2[n] = WkT[n,:]·bq
        const int n = wid - 768;
        float s = 0.f;
        for (int k = 0; k < 12; ++k) s += (float)WkT[(size_t)n * 768 + lane + 64 * k] * bq[lane + 64 * k];
        for (int o = 32; o; o >>= 1) s += __shfl_xor(s, o);
        if (lane == 0) w2f[n] = s;
    } else if (wid == 1536) {        // c0 -> bias_mg[768], 1 -> [769], 0 -> 770..799
        float s = 0.f;
        for (int k = 0; k < 12; ++k) s += bq[lane + 64 * k] * bk[lane + 64 * k];
        for (int o = 32; o; o >>= 1) s += __shfl_xor(s, o);
        if (lane < 32) {
            float v = 0.f;
            if (lane == 0) v = s;
            if (lane == 1) v = 1.f;
            bias_mg[768 + lane] = v;
        }
    } else if (wid < 1560) {         // bias_mg: zeros 0..767 ; bv -> 800..1376 ; 0 pads
        const int i = (wid - 1537) * 64 + lane;     // [0,1472)
        if (i < 768) bias_mg[i] = 0.f;
        else {
            const int j = i + 32;                   // 800..1503
            if (j < 1408) bias_mg[j] = (j < 1377) ? bv[j - 800] : 0.f;
        }
    } else if (wid < 1591) {         // zero Mt_aug rows 769..799
        const int r = 769 + (wid - 1560);
        for (int k = 0; k < 12; ++k) Mt_aug[(size_t)r * 768 + lane + 64 * k] = (_Float16)0.f;
    }
}

// e f32 [rows,768] -> e' f16 [rows,800]: cvt + col768=1 + col769=e·w2 + 770..799=0
__global__ void cvt_e_aug_kernel(const float* __restrict__ e, const float* __restrict__ w2f,
                                 _Float16* __restrict__ dst, int rows) {
    const int wpb = blockDim.x >> 6;
    int wid = blockIdx.x * wpb + (threadIdx.x >> 6);
    const int nw = gridDim.x * wpb;
    const int lane = threadIdx.x & 63;
    for (int s = wid; s < rows; s += nw) {
        const float4* er = (const float4*)(e + (size_t)s * 768);
        _Float16* dr = dst + (size_t)s * 800;
        float dot = 0.f;
#pragma unroll
        for (int k = 0; k < 3; ++k) {
            const int idx = lane + 64 * k;
            const float4 v = er[idx];
            const float4 w = ((const float4*)w2f)[idx];
            dot += v.x * w.x + v.y * w.y + v.z * w.z + v.w * w.w;
            f16x4 h;
            h[0] = (_Float16)v.x; h[1] = (_Float16)v.y;
            h[2] = (_Float16)v.z; h[3] = (_Float16)v.w;
            *(f16x4*)(dr + 4 * idx) = h;
        }
        for (int o = 32; o; o >>= 1) dot += __shfl_xor(dot, o);
        if (lane < 32) {
            _Float16 v = (_Float16)0.f;
            if (lane == 0) v = (_Float16)1.f;
            if (lane == 1) v = (_Float16)dot;
            dr[768 + lane] = v;
        }
    }
}

__device__ __forceinline__ void gload16(const _Float16* g, _Float16* l) {
    __builtin_amdgcn_global_load_lds(
        (const __attribute__((address_space(1))) unsigned int*)(g),
        (__attribute__((address_space(3))) unsigned int*)(l),
        16, 0, 0);
}

// overflow-safe fast tanh: 1 - 2*rcp(exp2(2log2e*x)+1)
__device__ __forceinline__ float fast_tanh(float x) {
    const float t = __builtin_amdgcn_exp2f(2.885390081777927f * x);
    return 1.f - 2.f * __builtin_amdgcn_rcpf(t + 1.f);
}

// ==== gemm256m: 256x128 (MxN) / BK=32 / 4 FAT waves (64x128) 3-stage ========
// Each wave: acc[4][8], 12 ds_read_b128 per 32 MFMA (vs 8/16 for 64x64).
// 256 threads; stage = A 4 chunks + B 2 chunks per thread -> vmcnt(6).
__global__ __launch_bounds__(256)
void gemm256m(const _Float16* __restrict__ A, const _Float16* __restrict__ Bt,
              const float* __restrict__ bias, _Float16* __restrict__ C,
              int M, int Nreal, int Nstore, int K,
              int lda, int ldb, int ldc, int nTileN)
{
    __shared__ __align__(16) _Float16 lds[3 * 12288];   // 3 x (A 16KB + B 8KB)

    int bid = blockIdx.x;
    {   // bijective XCD chunking (m204)
        const int nwg = gridDim.x;
        const int q8 = nwg >> 3, r8 = nwg & 7;
        const int xcd = bid & 7, loc = bid >> 3;
        bid = (xcd < r8 ? xcd * (q8 + 1) : r8 * (q8 + 1) + (xcd - r8) * q8) + loc;
    }
    const int tm = bid / nTileN, tn = bid - tm * nTileN;
    const int m0 = tm << 8, n0 = tn << 7;

    const int tid = threadIdx.x;
    const int lane = tid & 63;
    const int wm = tid >> 6;            // wave 0..3 owns rows wm*64..+63, all 128 cols

    // staging: A chunks tid+256k (k=0..3) -> rows (tid>>2)+64k ; B chunks tid, tid+256
    const int r0 = tid >> 2;
    const int c0 = (((tid & 3) ^ ((tid >> 3) & 3)) << 3);
    int ra0 = m0 + r0;        if (ra0 >= M) ra0 = M - 1;
    int ra1 = m0 + 64 + r0;   if (ra1 >= M) ra1 = M - 1;
    int ra2 = m0 + 128 + r0;  if (ra2 >= M) ra2 = M - 1;
    int ra3 = m0 + 192 + r0;  if (ra3 >= M) ra3 = M - 1;
    int rb0 = n0 + r0;        if (rb0 >= Nreal) rb0 = Nreal - 1;
    int rb1 = n0 + 64 + r0;   if (rb1 >= Nreal) rb1 = Nreal - 1;
    const _Float16* pA0 = A + (size_t)ra0 * lda + c0;
    const _Float16* pA1 = A + (size_t)ra1 * lda + c0;
    const _Float16* pA2 = A + (size_t)ra2 * lda + c0;
    const _Float16* pA3 = A + (size_t)ra3 * lda + c0;
    const _Float16* pB0 = Bt + (size_t)rb0 * ldb + c0;
    const _Float16* pB1 = Bt + (size_t)rb1 * ldb + c0;

    const int o0 = tid * 8;

    const int rr = lane & 15;
    const int hh = lane >> 4;
    const int sw = (rr >> 1) & 3;
    const int fAo = ((wm * 64 + rr) * 4 + (hh ^ sw)) * 8;   // + mi*512
    const int fBo = (rr * 4 + (hh ^ sw)) * 8;               // + nj*512 (B region)

    const f32x4 z4 = {0.f, 0.f, 0.f, 0.f};
    f32x4 acc[4][8];
#pragma unroll
    for (int i = 0; i < 4; ++i)
#pragma unroll
        for (int j = 0; j < 8; ++j) acc[i][j] = z4;

    const int nt = K >> 5;

#define STAGE(si, kt)                                              \
    do {                                                           \
        _Float16* base_ = lds + (si) * 12288;                      \
        const int ko_ = (kt) << 5;                                 \
        gload16(pA0 + ko_, base_ + o0);                            \
        gload16(pA1 + ko_, base_ + 2048 + o0);                     \
        gload16(pA2 + ko_, base_ + 4096 + o0);                     \
        gload16(pA3 + ko_, base_ + 6144 + o0);                     \
        gload16(pB0 + ko_, base_ + 8192 + o0);                     \
        gload16(pB1 + ko_, base_ + 10240 + o0);                    \
    } while (0)

#define COMPUTE(si)                                                            \
    do {                                                                       \
        const _Float16* cA_ = lds + (si) * 12288;                              \
        const _Float16* cB_ = cA_ + 8192;                                      \
        f16x8 a_[4], b_[8];                                                    \
        _Pragma("unroll")                                                      \
        for (int mi = 0; mi < 4; ++mi) a_[mi] = *(const f16x8*)(cA_ + fAo + mi * 512); \
        _Pragma("unroll")                                                      \
        for (int nj = 0; nj < 8; ++nj) b_[nj] = *(const f16x8*)(cB_ + fBo + nj * 512); \
        _Pragma("unroll")                                                      \
        for (int mi = 0; mi < 4; ++mi)                                         \
            _Pragma("unroll")                                                  \
            for (int nj = 0; nj < 8; ++nj)                                     \
                acc[mi][nj] = __builtin_amdgcn_mfma_f32_16x16x32_f16(          \
                    a_[mi], b_[nj], acc[mi][nj], 0, 0, 0);                     \
    } while (0)

    STAGE(0, 0);
    STAGE(1, 1);

    for (int j = 0; j < nt - 1; ++j) {
        asm volatile("s_waitcnt vmcnt(6)" ::: "memory");   // tile j's 6 loads done
        __builtin_amdgcn_s_barrier();
        __builtin_amdgcn_sched_barrier(0);
        if (j + 2 < nt) STAGE((j + 2) % 3, j + 2);
        COMPUTE(j % 3);
    }
    asm volatile("s_waitcnt vmcnt(0)" ::: "memory");
    __builtin_amdgcn_s_barrier();
    __builtin_amdgcn_sched_barrier(0);
    COMPUTE((nt - 1) % 3);

#undef STAGE
#undef COMPUTE

    // epilogue: bias -> f16 store (zero padded cols [Nreal, Nstore))
    const int cr0 = (lane >> 4) << 2;
    const int cc = lane & 15;
#pragma unroll
    for (int mi = 0; mi < 4; ++mi) {
#pragma unroll
        for (int nj = 0; nj < 8; ++nj) {
            const int gc = n0 + nj * 16 + cc;
            if (gc >= Nstore) continue;
            const bool real = gc < Nreal;
            const float bb = real ? bias[gc] : 0.f;
#pragma unroll
            for (int r = 0; r < 4; ++r) {
                const int gr = m0 + wm * 64 + mi * 16 + cr0 + r;
                if (gr >= M) continue;
                const float x = real ? (acc[mi][nj][r] + bb) : 0.f;
                C[(size_t)gr * ldc + gc] = (_Float16)x;
            }
        }
    }
}

// -------- 128x128 / BK=32 / 3-stage counted-vmcnt GEMM (R7, proven) ----------
template<bool TANH, bool OUT_F16, bool BIAS, int MODE>
__global__ __launch_bounds__(256)
void gemm_nt_f16(const _Float16* __restrict__ A, const _Float16* __restrict__ Bt,
                 const float* __restrict__ bias, void* __restrict__ Cp,
                 int M, int Nreal, int Nstore, int K,
                 int lda, int ldb, int ldc, int nTileN, int nTiles,
                 long long sA, long long sB, long long sC)
{
    __shared__ __align__(16) _Float16 lds[3 * 8192];

    int bid = blockIdx.x;
    int z, tm, tn;
    if (MODE == 0) {
        const int nwg = gridDim.x;
        const int q8 = nwg >> 3, r8 = nwg & 7;
        const int xcd = bid & 7, loc = bid >> 3;
        bid = (xcd < r8 ? xcd * (q8 + 1) : r8 * (q8 + 1) + (xcd - r8) * q8) + loc;
        z = 0;
        tm = bid / nTileN; tn = bid - tm * nTileN;
    } else {
        const int xcd = bid & 7, idx = bid >> 3;
        const int g = idx / nTiles, tile = idx - g * nTiles;
        z = g * 8 + xcd;
        tm = tile / nTileN; tn = tile - tm * nTileN;
    }
    const int m0 = tm << 7, n0 = tn << 7;

    const _Float16* Az = A + (size_t)z * sA;
    const _Float16* Bz = Bt + (size_t)z * sB;

    const int tid = threadIdx.x;
    const int lane = tid & 63;
    const int wid = tid >> 6;
    const int wm = wid >> 1, wn = wid & 1;

    const int r0 = tid >> 2;
    const int c0 = (((tid & 3) ^ ((tid >> 3) & 3)) << 3);
    const int rA0 = (m0 + r0      < M ? m0 + r0      : M - 1);
    const int rA1 = (m0 + r0 + 64 < M ? m0 + r0 + 64 : M - 1);
    const int rB0 = (n0 + r0      < Nreal ? n0 + r0      : Nreal - 1);
    const int rB1 = (n0 + r0 + 64 < Nreal ? n0 + r0 + 64 : Nreal - 1);
    const _Float16* pA0 = Az + (size_t)rA0 * lda + c0;
    const _Float16* pA1 = Az + (size_t)rA1 * lda + c0;
    const _Float16* pB0 = Bz + (size_t)rB0 * ldb + c0;
    const _Float16* pB1 = Bz + (size_t)rB1 * ldb + c0;

    const int o0 = tid * 8, o1 = (tid + 256) * 8;

    const int rr = lane & 15;
    const int hh = lane >> 4;
    const int sw = (rr >> 1) & 3;
    const int fAo = ((wm * 64 + rr) * 4 + (hh ^ sw)) * 8;
    const int fBo = ((wn * 64 + rr) * 4 + (hh ^ sw)) * 8;

    const f32x4 z4 = {0.f, 0.f, 0.f, 0.f};
    f32x4 acc[4][4];
#pragma unroll
    for (int i = 0; i < 4; ++i)
#pragma unroll
        for (int j = 0; j < 4; ++j) acc[i][j] = z4;

    const int nt = K >> 5;

#define STAGE(si, kt)                                              \
    do {                                                           \
        _Float16* base_ = lds + (si) * 8192;                       \
        const int ko_ = (kt) << 5;                                 \
        gload16(pA0 + ko_, base_ + o0);                            \
        gload16(pA1 + ko_, base_ + o1);                            \
        gload16(pB0 + ko_, base_ + 4096 + o0);                     \
        gload16(pB1 + ko_, base_ + 4096 + o1);                     \
    } while (0)

#define COMPUTE(si)                                                            \
    do {                                                                       \
        const _Float16* cA_ = lds + (si) * 8192;                               \
        const _Float16* cB_ = cA_ + 4096;                                      \
        f16x8 a_[4], b_[4];                                                    \
        _Pragma("unroll")                                                      \
        for (int mi = 0; mi < 4; ++mi) a_[mi] = *(const f16x8*)(cA_ + fAo + mi * 512); \
        _Pragma("unroll")                                                      \
        for (int ni = 0; ni < 4; ++ni) b_[ni] = *(const f16x8*)(cB_ + fBo + ni * 512); \
        _Pragma("unroll")                                                      \
        for (int mi = 0; mi < 4; ++mi)                                         \
            _Pragma("unroll")                                                  \
            for (int ni = 0; ni < 4; ++ni)                                     \
                acc[mi][ni] = __builtin_amdgcn_mfma_f32_16x16x32_f16(          \
                    a_[mi], b_[ni], acc[mi][ni], 0, 0, 0);                     \
    } while (0)

    STAGE(0, 0);
    STAGE(1, 1);

    for (int j = 0; j < nt - 1; ++j) {
        asm volatile("s_waitcnt vmcnt(4)" ::: "memory");
        __builtin_amdgcn_s_barrier();
        __builtin_amdgcn_sched_barrier(0);
        if (j + 2 < nt) STAGE((j + 2) % 3, j + 2);
        COMPUTE(j % 3);
    }
    asm volatile("s_waitcnt vmcnt(0)" ::: "memory");
    __builtin_amdgcn_s_barrier();
    __builtin_amdgcn_sched_barrier(0);
    COMPUTE((nt - 1) % 3);

#undef STAGE
#undef COMPUTE

    const int cr0 = (lane >> 4) << 2;
    const int cc = lane & 15;
    float*    Cf = (float*)Cp    + (size_t)z * sC;
    _Float16* Ch = (_Float16*)Cp + (size_t)z * sC;
#pragma unroll
    for (int mi = 0; mi < 4; ++mi) {
#pragma unroll
        for (int ni = 0; ni < 4; ++ni) {
            const int gc = n0 + wn * 64 + ni * 16 + cc;
            if (gc >= Nstore) continue;
            const bool real = gc < Nreal;
            float bb = 0.f;
            if (BIAS) bb = real ? bias[gc] : 0.f;
#pragma unroll
            for (int r = 0; r < 4; ++r) {
                const int gr = m0 + wm * 64 + mi * 16 + cr0 + r;
                if (gr >= M) continue;
                float x = real ? (acc[mi][ni][r] + bb) : 0.f;
                if (TANH) x = fast_tanh(x);
                if (OUT_F16) Ch[(size_t)gr * ldc + gc] = (_Float16)x;
                else         Cf[(size_t)gr * ldc + gc] = x;
            }
        }
    }
}

extern "C" void kernel_launch(void* const* d_in, const int* in_sizes, int n_in,
                              void* d_out, int out_size, void* d_ws, size_t ws_size,
                              hipStream_t stream)
{
    const float* b  = (const float*)d_in[0];
    const float* e  = (const float*)d_in[1];
    const float* Wq = (const float*)d_in[2];
    const float* bq = (const float*)d_in[3];
    const float* Wk = (const float*)d_in[4];
    const float* bk = (const float*)d_in[5];
    const float* Wv = (const float*)d_in[6];
    const float* bv = (const float*)d_in[7];
    float* out = (float*)d_out;

    const int BT = 36928, T = 577, S = 577, Sp = 608, Kb = 800;
    const int Nmg = 1408;   // merged B rows: 800 aug + 608 v-slot

    // ws layout (f16 units): ~212.5 MB total
    _Float16* WqT_h  = (_Float16*)d_ws;                      // 589824
    _Float16* WkT_h  = WqT_h + 589824;                       // 589824
    _Float16* Mt_aug = WkT_h + 589824;                       // 800*768 (B rows 0..799)
    _Float16* Wv_h   = Mt_aug + 614400;                      // 577*768 (B rows 800..1376)
    float*    bias_mg = (float*)(Wv_h + 443136);             // 1408 f32 (2816 hw)
    float*    w2f     = (float*)((_Float16*)bias_mg + 2816); // 768 f32 (1536 hw)
    _Float16* S1    = (_Float16*)w2f + 1536;                 // b_h [BT,768] then e' [BT,800]
    _Float16* S_big = S1 + (size_t)BT * Kb;                  // [BT,1408]
    _Float16* S4    = S_big + (size_t)BT * Nmg;              // attn [BT,608]

    // weight preprocessing
    cvtT2_kernel<<<dim3(24, 24, 2), 256, 0, stream>>>(Wq, WqT_h, Wk, WkT_h);
    cvt8_kernel<<<217, 256, 0, stream>>>(Wv, Wv_h, 55392);
    prep_kernel<<<398, 256, 0, stream>>>(WqT_h, WkT_h, bq, bk, bv, w2f, Mt_aug, bias_mg);
    // Mt = NT(WkT, WqT)  [768x768] -> Mt_aug rows 0..767
    gemm_nt_f16<false, true, false, 0><<<dim3(36, 1, 1), 256, 0, stream>>>(
        WkT_h, WqT_h, nullptr, Mt_aug, 768, 768, 768, 768, 768, 768, 768, 6, 0, 0, 0, 0);

    // b -> f16
    cvt8_kernel<<<2048, 256, 0, stream>>>(b, S1, 3545088);
    // S_big = b_h @ B_merged^T + bias_mg   [BT,1408]  (145 x 11 tiles of 256x128)
    gemm256m<<<dim3(1595, 1, 1), 256, 0, stream>>>(
        S1, Mt_aug, bias_mg, S_big, BT, 1377, Nmg, 768, 768, 768, Nmg, 11);
    // e' (overwrites b_h, dead)
    cvt_e_aug_kernel<<<2048, 256, 0, stream>>>(e, w2f, S1, BT);
    // attn = tanh(NT(S_big[:,0:800], e'))  batched [64][577,608], K=800
    gemm_nt_f16<true, true, false, 1><<<dim3(1600, 1, 1), 256, 0, stream>>>(
        S_big, S1, nullptr, S4, T, S, Sp, Kb, Nmg, Kb, Sp, 5, 25,
        (long long)T * Nmg, (long long)T * Kb, (long long)T * Sp);
    // out = NT(attn, S_big[:,800:1408])  batched [64][577,577] f32, K=608
    gemm_nt_f16<false, false, false, 1><<<dim3(1600, 1, 1), 256, 0, stream>>>(
        S4, S_big + 800, nullptr, out, T, T, T, Sp, Sp, Nmg, T, 5, 25,
        (long long)T * Sp, (long long)T * Nmg, (long long)T * T);
}

// Round 18
// 388.895 us; speedup vs baseline: 1.1199x; 1.1199x over previous
//
#include <hip/hip_runtime.h>
#include <hip/hip_fp16.h>

// Pipeline (all fp16 MFMA, f32 accum), R7-proven 3-stage GEMM structure:
//   Algebraic fusion (R10): q·k^T = b(Wq^T Wk)e^T + row[t] + col[s], with
//   row[t] = b·(Wq^T bk) + bq·bk (= S_big col 768), col[s] = e·(Wk^T bq).
//   Merged projection (R11): S_big = b_h @ [Mt|w1|0|Wv]^T + bias  [BT,1408]
//     cols 0..767 = bM (attn A), col 768 = row-term, cols 800..1407 = v.
//   R18: attn K = 768 (24 steps, was 800); row/col bias terms added in the
//     attn EPILOGUE (row from S_big col 768 f16, col from f32 array written
//     by cvt_e). B operand = plain e_f16 [BT,768].
//   out = NT(attn, S_big[,800:])  batched, K=608, f32 out.
// gemm256m (R16, proven 125us): 256x128 tile, 8 waves (4Mx2N of 64x64),
//   3-stage counted-vmcnt, 3 loads/thread/stage -> vmcnt(3), LDS 72 KB.
// gemm_nt_f16 (R7): 128x128, BK=32, 3-stage, vmcnt(4).
// R15: fast tanh: tanh(x) = 1 - 2*rcp(exp2(2log2e*x)+1).
// XOR-swizzled LDS slots (R6): chunk c -> row c>>2, col ((c&3)^((c>>3)&3))*8;
// read lane l row r: chunk r*4 + ((l>>4)^((r>>1)&3)). 0 conflicts + coalesced.
// MODE0 = bijective XCD chunking; MODE1 = batch->XCD co-location.
// NOTE (R8/R12/R13/R14/R17): K=768 too shallow for 8-phase/BK64/fat-wave
// schedules -- occupancy-rich 3-stage with 8 thin waves is the structure.

typedef _Float16 f16x8 __attribute__((ext_vector_type(8)));
typedef _Float16 f16x4 __attribute__((ext_vector_type(4)));
typedef float f32x4 __attribute__((ext_vector_type(4)));

__global__ void cvt8_kernel(const float* __restrict__ src, _Float16* __restrict__ dst,
                            long long n8) {
    long long i = blockIdx.x * (long long)blockDim.x + threadIdx.x;
    const long long stride = gridDim.x * (long long)blockDim.x;
    for (; i < n8; i += stride) {
        const float4 f0 = ((const float4*)src)[2 * i];
        const float4 f1 = ((const float4*)src)[2 * i + 1];
        f16x8 h;
        h[0] = (_Float16)f0.x; h[1] = (_Float16)f0.y; h[2] = (_Float16)f0.z; h[3] = (_Float16)f0.w;
        h[4] = (_Float16)f1.x; h[5] = (_Float16)f1.y; h[6] = (_Float16)f1.z; h[7] = (_Float16)f1.w;
        ((f16x8*)dst)[i] = h;
    }
}

// two f32 [768,768] -> f16 transposed [768,768] (z selects matrix)
__global__ void cvtT2_kernel(const float* __restrict__ s0, _Float16* __restrict__ d0,
                             const float* __restrict__ s1, _Float16* __restrict__ d1) {
    __shared__ float t[32][33];
    const float* src = blockIdx.z ? s1 : s0;
    _Float16* dst = blockIdx.z ? d1 : d0;
    const int bx = blockIdx.x, by = blockIdx.y;
    const int tx = threadIdx.x & 31, ty = threadIdx.x >> 5;
#pragma unroll
    for (int k = 0; k < 4; ++k) {
        const int r = ty + 8 * k;
        t[r][tx] = src[(size_t)(by * 32 + r) * 768 + bx * 32 + tx];
    }
    __syncthreads();
#pragma unroll
    for (int k = 0; k < 4; ++k) {
        const int r = ty + 8 * k;
        dst[(size_t)(bx * 32 + r) * 768 + by * 32 + tx] = (_Float16)t[tx][r];
    }
}

// w1 -> Mt_aug row 768 ; w2f ; bias_mg[1408] ; zero Mt_aug rows 769..799
__global__ void prep_kernel(const _Float16* __restrict__ WqT, const _Float16* __restrict__ WkT,
                            const float* __restrict__ bq, const float* __restrict__ bk,
                            const float* __restrict__ bv,
                            float* __restrict__ w2f, _Float16* __restrict__ Mt_aug,
                            float* __restrict__ bias_mg) {
    const int wid = blockIdx.x * 4 + (threadIdx.x >> 6);
    const int lane = threadIdx.x & 63;
    if (wid < 768) {                 // w1[wid] = WqT[wid,:]·bk
        float s = 0.f;
        for (int k = 0; k < 12; ++k) s += (float)WqT[(size_t)wid * 768 + lane + 64 * k] * bk[lane + 64 * k];
        for (int o = 32; o; o >>= 1) s += __shfl_xor(s, o);
        if (lane == 0) Mt_aug[(size_t)768 * 768 + wid] = (_Float16)s;
    } else if (wid < 1536) {         // w2[n] = WkT[n,:]·bq
        const int n = wid - 768;
        float s = 0.f;
        for (int k = 0; k < 12; ++k) s += (float)WkT[(size_t)n * 768 + lane + 64 * k] * bq[lane + 64 * k];
        for (int o = 32; o; o >>= 1) s += __shfl_xor(s, o);
        if (lane == 0) w2f[n] = s;
    } else if (wid == 1536) {        // c0 -> bias_mg[768], 1 -> [769], 0 -> 770..799
        float s = 0.f;
        for (int k = 0; k < 12; ++k) s += bq[lane + 64 * k] * bk[lane + 64 * k];
        for (int o = 32; o; o >>= 1) s += __shfl_xor(s, o);
        if (lane < 32) {
            float v = 0.f;
            if (lane == 0) v = s;
            if (lane == 1) v = 1.f;
            bias_mg[768 + lane] = v;
        }
    } else if (wid < 1560) {         // bias_mg: zeros 0..767 ; bv -> 800..1376 ; 0 pads
        const int i = (wid - 1537) * 64 + lane;     // [0,1472)
        if (i < 768) bias_mg[i] = 0.f;
        else {
            const int j = i + 32;                   // 800..1503
            if (j < 1408) bias_mg[j] = (j < 1377) ? bv[j - 800] : 0.f;
        }
    } else if (wid < 1591) {         // zero Mt_aug rows 769..799
        const int r = 769 + (wid - 1560);
        for (int k = 0; k < 12; ++k) Mt_aug[(size_t)r * 768 + lane + 64 * k] = (_Float16)0.f;
    }
}

// e f32 [rows,768] -> e_f16 [rows,768] + colB[s] = e[s]·w2 (f32)
__global__ void cvt_e_kernel(const float* __restrict__ e, const float* __restrict__ w2f,
                             _Float16* __restrict__ dst, float* __restrict__ colB,
                             int rows) {
    const int wpb = blockDim.x >> 6;
    int wid = blockIdx.x * wpb + (threadIdx.x >> 6);
    const int nw = gridDim.x * wpb;
    const int lane = threadIdx.x & 63;
    for (int s = wid; s < rows; s += nw) {
        const float4* er = (const float4*)(e + (size_t)s * 768);
        _Float16* dr = dst + (size_t)s * 768;
        float dot = 0.f;
#pragma unroll
        for (int k = 0; k < 3; ++k) {
            const int idx = lane + 64 * k;
            const float4 v = er[idx];
            const float4 w = ((const float4*)w2f)[idx];
            dot += v.x * w.x + v.y * w.y + v.z * w.z + v.w * w.w;
            f16x4 h;
            h[0] = (_Float16)v.x; h[1] = (_Float16)v.y;
            h[2] = (_Float16)v.z; h[3] = (_Float16)v.w;
            *(f16x4*)(dr + 4 * idx) = h;
        }
        for (int o = 32; o; o >>= 1) dot += __shfl_xor(dot, o);
        if (lane == 0) colB[s] = dot;
    }
}

__device__ __forceinline__ void gload16(const _Float16* g, _Float16* l) {
    __builtin_amdgcn_global_load_lds(
        (const __attribute__((address_space(1))) unsigned int*)(g),
        (__attribute__((address_space(3))) unsigned int*)(l),
        16, 0, 0);
}

// overflow-safe fast tanh: 1 - 2*rcp(exp2(2log2e*x)+1)
__device__ __forceinline__ float fast_tanh(float x) {
    const float t = __builtin_amdgcn_exp2f(2.885390081777927f * x);
    return 1.f - 2.f * __builtin_amdgcn_rcpf(t + 1.f);
}

// ======== gemm256m: 256x128 (MxN) / BK=32 / 8-wave 3-stage (R16) ===========
// 8 waves (4M x 2N of 64x64); 3 loads/stage/thread -> vmcnt(3); LDS 72 KB.
__global__ __launch_bounds__(512)
void gemm256m(const _Float16* __restrict__ A, const _Float16* __restrict__ Bt,
              const float* __restrict__ bias, _Float16* __restrict__ C,
              int M, int Nreal, int Nstore, int K,
              int lda, int ldb, int ldc, int nTileN)
{
    __shared__ __align__(16) _Float16 lds[3 * 12288];   // 3 x (A 16KB + B 8KB)

    int bid = blockIdx.x;
    {   // bijective XCD chunking (m204)
        const int nwg = gridDim.x;
        const int q8 = nwg >> 3, r8 = nwg & 7;
        const int xcd = bid & 7, loc = bid >> 3;
        bid = (xcd < r8 ? xcd * (q8 + 1) : r8 * (q8 + 1) + (xcd - r8) * q8) + loc;
    }
    const int tm = bid / nTileN, tn = bid - tm * nTileN;
    const int m0 = tm << 8, n0 = tn << 7;

    const int tid = threadIdx.x;
    const int lane = tid & 63;
    const int wid = tid >> 6;
    const int wm = wid >> 1;            // 0..3 M quarter (64 rows)
    const int wn = wid & 1;             // 0..1 N half (64 cols)

    const int r0 = tid >> 2;
    const int c0 = (((tid & 3) ^ ((tid >> 3) & 3)) << 3);
    int ra0 = m0 + r0;        if (ra0 >= M) ra0 = M - 1;
    int ra1 = m0 + 128 + r0;  if (ra1 >= M) ra1 = M - 1;
    int rb0 = n0 + r0;        if (rb0 >= Nreal) rb0 = Nreal - 1;
    const _Float16* pA0 = A + (size_t)ra0 * lda + c0;
    const _Float16* pA1 = A + (size_t)ra1 * lda + c0;
    const _Float16* pB0 = Bt + (size_t)rb0 * ldb + c0;

    const int o0 = tid * 8, o1 = (tid + 512) * 8;

    const int rr = lane & 15;
    const int hh = lane >> 4;
    const int sw = (rr >> 1) & 3;
    const int fAo = ((wm * 64 + rr) * 4 + (hh ^ sw)) * 8;
    const int fBo = ((wn * 64 + rr) * 4 + (hh ^ sw)) * 8;

    const f32x4 z4 = {0.f, 0.f, 0.f, 0.f};
    f32x4 acc[4][4];
#pragma unroll
    for (int i = 0; i < 4; ++i)
#pragma unroll
        for (int j = 0; j < 4; ++j) acc[i][j] = z4;

    const int nt = K >> 5;

#define STAGE(si, kt)                                              \
    do {                                                           \
        _Float16* base_ = lds + (si) * 12288;                      \
        const int ko_ = (kt) << 5;                                 \
        gload16(pA0 + ko_, base_ + o0);                            \
        gload16(pA1 + ko_, base_ + o1);                            \
        gload16(pB0 + ko_, base_ + 8192 + o0);                     \
    } while (0)

#define COMPUTE(si)                                                            \
    do {                                                                       \
        const _Float16* cA_ = lds + (si) * 12288;                              \
        const _Float16* cB_ = cA_ + 8192;                                      \
        f16x8 a_[4], b_[4];                                                    \
        _Pragma("unroll")                                                      \
        for (int mi = 0; mi < 4; ++mi) a_[mi] = *(const f16x8*)(cA_ + fAo + mi * 512); \
        _Pragma("unroll")                                                      \
        for (int ni = 0; ni < 4; ++ni) b_[ni] = *(const f16x8*)(cB_ + fBo + ni * 512); \
        _Pragma("unroll")                                                      \
        for (int mi = 0; mi < 4; ++mi)                                         \
            _Pragma("unroll")                                                  \
            for (int ni = 0; ni < 4; ++ni)                                     \
                acc[mi][ni] = __builtin_amdgcn_mfma_f32_16x16x32_f16(          \
                    a_[mi], b_[ni], acc[mi][ni], 0, 0, 0);                     \
    } while (0)

    STAGE(0, 0);
    STAGE(1, 1);

    for (int j = 0; j < nt - 1; ++j) {
        asm volatile("s_waitcnt vmcnt(3)" ::: "memory");
        __builtin_amdgcn_s_barrier();
        __builtin_amdgcn_sched_barrier(0);
        if (j + 2 < nt) STAGE((j + 2) % 3, j + 2);
        COMPUTE(j % 3);
    }
    asm volatile("s_waitcnt vmcnt(0)" ::: "memory");
    __builtin_amdgcn_s_barrier();
    __builtin_amdgcn_sched_barrier(0);
    COMPUTE((nt - 1) % 3);

#undef STAGE
#undef COMPUTE

    const int cr0 = (lane >> 4) << 2;
    const int cc = lane & 15;
#pragma unroll
    for (int mi = 0; mi < 4; ++mi) {
#pragma unroll
        for (int ni = 0; ni < 4; ++ni) {
            const int gc = n0 + wn * 64 + ni * 16 + cc;
            if (gc >= Nstore) continue;
            const bool real = gc < Nreal;
            const float bb = real ? bias[gc] : 0.f;
#pragma unroll
            for (int r = 0; r < 4; ++r) {
                const int gr = m0 + wm * 64 + mi * 16 + cr0 + r;
                if (gr >= M) continue;
                const float x = real ? (acc[mi][ni][r] + bb) : 0.f;
                C[(size_t)gr * ldc + gc] = (_Float16)x;
            }
        }
    }
}

// ---- gemm_attn: 128x128 / BK=32 / 3-stage, batched, epilogue row/col+tanh --
__global__ __launch_bounds__(256)
void gemm_attn(const _Float16* __restrict__ A, const _Float16* __restrict__ Bt,
               const float* __restrict__ colB, _Float16* __restrict__ C,
               int M, int Nreal, int Nstore, int K,
               int lda, int ldb, int ldc, int nTileN, int nTiles,
               long long sA, long long sB, long long sC)
{
    __shared__ __align__(16) _Float16 lds[3 * 8192];

    int bid = blockIdx.x;
    const int xcd = bid & 7, idx = bid >> 3;
    const int g = idx / nTiles, tile = idx - g * nTiles;
    const int z = g * 8 + xcd;
    const int tm = tile / nTileN, tn = tile - tm * nTileN;
    const int m0 = tm << 7, n0 = tn << 7;

    const _Float16* Az = A + (size_t)z * sA;
    const _Float16* Bz = Bt + (size_t)z * sB;
    const float* colBz = colB + (size_t)z * 577;

    const int tid = threadIdx.x;
    const int lane = tid & 63;
    const int wid = tid >> 6;
    const int wm = wid >> 1, wn = wid & 1;

    const int r0 = tid >> 2;
    const int c0 = (((tid & 3) ^ ((tid >> 3) & 3)) << 3);
    const int rA0 = (m0 + r0      < M ? m0 + r0      : M - 1);
    const int rA1 = (m0 + r0 + 64 < M ? m0 + r0 + 64 : M - 1);
    const int rB0 = (n0 + r0      < Nreal ? n0 + r0      : Nreal - 1);
    const int rB1 = (n0 + r0 + 64 < Nreal ? n0 + r0 + 64 : Nreal - 1);
    const _Float16* pA0 = Az + (size_t)rA0 * lda + c0;
    const _Float16* pA1 = Az + (size_t)rA1 * lda + c0;
    const _Float16* pB0 = Bz + (size_t)rB0 * ldb + c0;
    const _Float16* pB1 = Bz + (size_t)rB1 * ldb + c0;

    const int o0 = tid * 8, o1 = (tid + 256) * 8;

    const int rr = lane & 15;
    const int hh = lane >> 4;
    const int sw = (rr >> 1) & 3;
    const int fAo = ((wm * 64 + rr) * 4 + (hh ^ sw)) * 8;
    const int fBo = ((wn * 64 + rr) * 4 + (hh ^ sw)) * 8;

    const f32x4 z4 = {0.f, 0.f, 0.f, 0.f};
    f32x4 acc[4][4];
#pragma unroll
    for (int i = 0; i < 4; ++i)
#pragma unroll
        for (int j = 0; j < 4; ++j) acc[i][j] = z4;

    const int nt = K >> 5;

#define STAGE(si, kt)                                              \
    do {                                                           \
        _Float16* base_ = lds + (si) * 8192;                       \
        const int ko_ = (kt) << 5;                                 \
        gload16(pA0 + ko_, base_ + o0);                            \
        gload16(pA1 + ko_, base_ + o1);                            \
        gload16(pB0 + ko_, base_ + 4096 + o0);                     \
        gload16(pB1 + ko_, base_ + 4096 + o1);                     \
    } while (0)

#define COMPUTE(si)                                                            \
    do {                                                                       \
        const _Float16* cA_ = lds + (si) * 8192;                               \
        const _Float16* cB_ = cA_ + 4096;                                      \
        f16x8 a_[4], b_[4];                                                    \
        _Pragma("unroll")                                                      \
        for (int mi = 0; mi < 4; ++mi) a_[mi] = *(const f16x8*)(cA_ + fAo + mi * 512); \
        _Pragma("unroll")                                                      \
        for (int ni = 0; ni < 4; ++ni) b_[ni] = *(const f16x8*)(cB_ + fBo + ni * 512); \
        _Pragma("unroll")                                                      \
        for (int mi = 0; mi < 4; ++mi)                                         \
            _Pragma("unroll")                                                  \
            for (int ni = 0; ni < 4; ++ni)                                     \
                acc[mi][ni] = __builtin_amdgcn_mfma_f32_16x16x32_f16(          \
                    a_[mi], b_[ni], acc[mi][ni], 0, 0, 0);                     \
    } while (0)

    STAGE(0, 0);
    STAGE(1, 1);

    for (int j = 0; j < nt - 1; ++j) {
        asm volatile("s_waitcnt vmcnt(4)" ::: "memory");
        __builtin_amdgcn_s_barrier();
        __builtin_amdgcn_sched_barrier(0);
        if (j + 2 < nt) STAGE((j + 2) % 3, j + 2);
        COMPUTE(j % 3);
    }
    asm volatile("s_waitcnt vmcnt(0)" ::: "memory");
    __builtin_amdgcn_s_barrier();
    __builtin_amdgcn_sched_barrier(0);
    COMPUTE((nt - 1) % 3);

#undef STAGE
#undef COMPUTE

    // epilogue: x = tanh(acc + row[t] + col[s]); zero padded cols
    const int cr0 = (lane >> 4) << 2;
    const int cc = lane & 15;
    _Float16* Cz = C + (size_t)z * sC;
    float rowt[4][4];
#pragma unroll
    for (int mi = 0; mi < 4; ++mi)
#pragma unroll
        for (int r = 0; r < 4; ++r) {
            const int gr = m0 + wm * 64 + mi * 16 + cr0 + r;
            rowt[mi][r] = (gr < M) ? (float)Az[(size_t)gr * lda + 768] : 0.f;
        }
#pragma unroll
    for (int mi = 0; mi < 4; ++mi) {
#pragma unroll
        for (int ni = 0; ni < 4; ++ni) {
            const int gc = n0 + wn * 64 + ni * 16 + cc;
            if (gc >= Nstore) continue;
            const bool real = gc < Nreal;
            const float colt = real ? colBz[gc] : 0.f;
#pragma unroll
            for (int r = 0; r < 4; ++r) {
                const int gr = m0 + wm * 64 + mi * 16 + cr0 + r;
                if (gr >= M) continue;
                const float x = real ? fast_tanh(acc[mi][ni][r] + rowt[mi][r] + colt) : 0.f;
                Cz[(size_t)gr * ldc + gc] = (_Float16)x;
            }
        }
    }
}

// -------- 128x128 / BK=32 / 3-stage counted-vmcnt GEMM (R7, proven) ----------
template<bool TANH, bool OUT_F16, bool BIAS, int MODE>
__global__ __launch_bounds__(256)
void gemm_nt_f16(const _Float16* __restrict__ A, const _Float16* __restrict__ Bt,
                 const float* __restrict__ bias, void* __restrict__ Cp,
                 int M, int Nreal, int Nstore, int K,
                 int lda, int ldb, int ldc, int nTileN, int nTiles,
                 long long sA, long long sB, long long sC)
{
    __shared__ __align__(16) _Float16 lds[3 * 8192];

    int bid = blockIdx.x;
    int z, tm, tn;
    if (MODE == 0) {
        const int nwg = gridDim.x;
        const int q8 = nwg >> 3, r8 = nwg & 7;
        const int xcd = bid & 7, loc = bid >> 3;
        bid = (xcd < r8 ? xcd * (q8 + 1) : r8 * (q8 + 1) + (xcd - r8) * q8) + loc;
        z = 0;
        tm = bid / nTileN; tn = bid - tm * nTileN;
    } else {
        const int xcd = bid & 7, idx = bid >> 3;
        const int g = idx / nTiles, tile = idx - g * nTiles;
        z = g * 8 + xcd;
        tm = tile / nTileN; tn = tile - tm * nTileN;
    }
    const int m0 = tm << 7, n0 = tn << 7;

    const _Float16* Az = A + (size_t)z * sA;
    const _Float16* Bz = Bt + (size_t)z * sB;

    const int tid = threadIdx.x;
    const int lane = tid & 63;
    const int wid = tid >> 6;
    const int wm = wid >> 1, wn = wid & 1;

    const int r0 = tid >> 2;
    const int c0 = (((tid & 3) ^ ((tid >> 3) & 3)) << 3);
    const int rA0 = (m0 + r0      < M ? m0 + r0      : M - 1);
    const int rA1 = (m0 + r0 + 64 < M ? m0 + r0 + 64 : M - 1);
    const int rB0 = (n0 + r0      < Nreal ? n0 + r0      : Nreal - 1);
    const int rB1 = (n0 + r0 + 64 < Nreal ? n0 + r0 + 64 : Nreal - 1);
    const _Float16* pA0 = Az + (size_t)rA0 * lda + c0;
    const _Float16* pA1 = Az + (size_t)rA1 * lda + c0;
    const _Float16* pB0 = Bz + (size_t)rB0 * ldb + c0;
    const _Float16* pB1 = Bz + (size_t)rB1 * ldb + c0;

    const int o0 = tid * 8, o1 = (tid + 256) * 8;

    const int rr = lane & 15;
    const int hh = lane >> 4;
    const int sw = (rr >> 1) & 3;
    const int fAo = ((wm * 64 + rr) * 4 + (hh ^ sw)) * 8;
    const int fBo = ((wn * 64 + rr) * 4 + (hh ^ sw)) * 8;

    const f32x4 z4 = {0.f, 0.f, 0.f, 0.f};
    f32x4 acc[4][4];
#pragma unroll
    for (int i = 0; i < 4; ++i)
#pragma unroll
        for (int j = 0; j < 4; ++j) acc[i][j] = z4;

    const int nt = K >> 5;

#define STAGE(si, kt)                                              \
    do {                                                           \
        _Float16* base_ = lds + (si) * 8192;                       \
        const int ko_ = (kt) << 5;                                 \
        gload16(pA0 + ko_, base_ + o0);                            \
        gload16(pA1 + ko_, base_ + o1);                            \
        gload16(pB0 + ko_, base_ + 4096 + o0);                     \
        gload16(pB1 + ko_, base_ + 4096 + o1);                     \
    } while (0)

#define COMPUTE(si)                                                            \
    do {                                                                       \
        const _Float16* cA_ = lds + (si) * 8192;                               \
        const _Float16* cB_ = cA_ + 4096;                                      \
        f16x8 a_[4], b_[4];                                                    \
        _Pragma("unroll")                                                      \
        for (int mi = 0; mi < 4; ++mi) a_[mi] = *(const f16x8*)(cA_ + fAo + mi * 512); \
        _Pragma("unroll")                                                      \
        for (int ni = 0; ni < 4; ++ni) b_[ni] = *(const f16x8*)(cB_ + fBo + ni * 512); \
        _Pragma("unroll")                                                      \
        for (int mi = 0; mi < 4; ++mi)                                         \
            _Pragma("unroll")                                                  \
            for (int ni = 0; ni < 4; ++ni)                                     \
                acc[mi][ni] = __builtin_amdgcn_mfma_f32_16x16x32_f16(          \
                    a_[mi], b_[ni], acc[mi][ni], 0, 0, 0);                     \
    } while (0)

    STAGE(0, 0);
    STAGE(1, 1);

    for (int j = 0; j < nt - 1; ++j) {
        asm volatile("s_waitcnt vmcnt(4)" ::: "memory");
        __builtin_amdgcn_s_barrier();
        __builtin_amdgcn_sched_barrier(0);
        if (j + 2 < nt) STAGE((j + 2) % 3, j + 2);
        COMPUTE(j % 3);
    }
    asm volatile("s_waitcnt vmcnt(0)" ::: "memory");
    __builtin_amdgcn_s_barrier();
    __builtin_amdgcn_sched_barrier(0);
    COMPUTE((nt - 1) % 3);

#undef STAGE
#undef COMPUTE

    const int cr0 = (lane >> 4) << 2;
    const int cc = lane & 15;
    float*    Cf = (float*)Cp    + (size_t)z * sC;
    _Float16* Ch = (_Float16*)Cp + (size_t)z * sC;
#pragma unroll
    for (int mi = 0; mi < 4; ++mi) {
#pragma unroll
        for (int ni = 0; ni < 4; ++ni) {
            const int gc = n0 + wn * 64 + ni * 16 + cc;
            if (gc >= Nstore) continue;
            const bool real = gc < Nreal;
            float bb = 0.f;
            if (BIAS) bb = real ? bias[gc] : 0.f;
#pragma unroll
            for (int r = 0; r < 4; ++r) {
                const int gr = m0 + wm * 64 + mi * 16 + cr0 + r;
                if (gr >= M) continue;
                float x = real ? (acc[mi][ni][r] + bb) : 0.f;
                if (TANH) x = fast_tanh(x);
                if (OUT_F16) Ch[(size_t)gr * ldc + gc] = (_Float16)x;
                else         Cf[(size_t)gr * ldc + gc] = x;
            }
        }
    }
}

extern "C" void kernel_launch(void* const* d_in, const int* in_sizes, int n_in,
                              void* d_out, int out_size, void* d_ws, size_t ws_size,
                              hipStream_t stream)
{
    const float* b  = (const float*)d_in[0];
    const float* e  = (const float*)d_in[1];
    const float* Wq = (const float*)d_in[2];
    const float* bq = (const float*)d_in[3];
    const float* Wk = (const float*)d_in[4];
    const float* bk = (const float*)d_in[5];
    const float* Wv = (const float*)d_in[6];
    const float* bv = (const float*)d_in[7];
    float* out = (float*)d_out;

    const int BT = 36928, T = 577, S = 577, Sp = 608, D = 768;
    const int Nmg = 1408;   // merged B rows: 800 aug + 608 v-slot

    // ws layout (f16 units): ~210 MB total
    _Float16* WqT_h  = (_Float16*)d_ws;                      // 589824
    _Float16* WkT_h  = WqT_h + 589824;                       // 589824
    _Float16* Mt_aug = WkT_h + 589824;                       // 800*768 (B rows 0..799)
    _Float16* Wv_h   = Mt_aug + 614400;                      // 577*768 (B rows 800..1376)
    float*    bias_mg = (float*)(Wv_h + 443136);             // 1408 f32
    float*    w2f     = bias_mg + 1408;                      // 768 f32
    float*    colB    = w2f + 768;                           // BT f32 (col-term)
    _Float16* S1    = (_Float16*)(colB + BT);                // b_h / e_f16 [BT,768]
    _Float16* S_big = S1 + (size_t)BT * D;                   // [BT,1408]
    _Float16* S4    = S_big + (size_t)BT * Nmg;              // attn [BT,608]

    // weight preprocessing
    cvtT2_kernel<<<dim3(24, 24, 2), 256, 0, stream>>>(Wq, WqT_h, Wk, WkT_h);
    cvt8_kernel<<<217, 256, 0, stream>>>(Wv, Wv_h, 55392);
    prep_kernel<<<398, 256, 0, stream>>>(WqT_h, WkT_h, bq, bk, bv, w2f, Mt_aug, bias_mg);
    // Mt = NT(WkT, WqT)  [768x768] -> Mt_aug rows 0..767
    gemm_nt_f16<false, true, false, 0><<<dim3(36, 1, 1), 256, 0, stream>>>(
        WkT_h, WqT_h, nullptr, Mt_aug, 768, 768, 768, 768, 768, 768, 768, 6, 0, 0, 0, 0);

    // b -> f16
    cvt8_kernel<<<2048, 256, 0, stream>>>(b, S1, 3545088);
    // S_big = b_h @ B_merged^T + bias_mg   [BT,1408]  (145 x 11 tiles of 256x128)
    gemm256m<<<dim3(1595, 1, 1), 512, 0, stream>>>(
        S1, Mt_aug, bias_mg, S_big, BT, 1377, Nmg, 768, 768, 768, Nmg, 11);
    // e -> f16 + col-term (overwrites b_h, dead)
    cvt_e_kernel<<<2048, 256, 0, stream>>>(e, w2f, S1, colB, BT);
    // attn = tanh(NT(S_big[:,0:768], e_f16) + row + col)  batched, K=768
    gemm_attn<<<dim3(1600, 1, 1), 256, 0, stream>>>(
        S_big, S1, colB, S4, T, S, Sp, D, Nmg, D, Sp, 5, 25,
        (long long)T * Nmg, (long long)T * D, (long long)T * Sp);
    // out = NT(attn, S_big[:,800:1408])  batched [64][577,577] f32, K=608
    gemm_nt_f16<false, false, false, 1><<<dim3(1600, 1, 1), 256, 0, stream>>>(
        S4, S_big + 800, nullptr, out, T, T, T, Sp, Sp, Nmg, T, 5, 25,
        (long long)T * Sp, (long long)T * Nmg, (long long)T * T);
}

// Round 19
// 338.493 us; speedup vs baseline: 1.2867x; 1.1489x over previous
//
#include <hip/hip_runtime.h>
#include <hip/hip_fp16.h>

// Pipeline (all fp16 MFMA, f32 accum), R7-proven 3-stage GEMM structure:
//   Algebraic fusion (R10): q·k^T = b(Wq^T Wk)e^T + b·w1 + (e·w2) + c0.
//   Merged projection (R11): S_big = b_h @ [Mt|w1|0|Wv]^T + bias  [BT,1408]
//     cols 0..799 = bm' (attn A), cols 800..1407 = v (out B).
//   attn = tanh(NT(S_big[,0:800], e'))  batched ; out = NT(attn, S_big[,800:]).
// R16 (BEST, 338 us): gemm256m = 256x128 tile, 8 waves (4Mx2N of 64x64),
//   3-stage counted-vmcnt, 3 loads/thread/stage -> vmcnt(3), LDS 72 KB ->
//   2 blocks/CU. Batched GEMMs stay 128^2 (R7 kernel, vmcnt(4), 3 blocks/CU).
// R15: fast tanh epilogue: tanh(x) = 1 - 2*rcp(exp2(2log2e*x)+1).
// XOR-swizzled LDS slots (verified R6): chunk c -> row c>>2, col
// ((c&3)^((c>>3)&3))*8; read lane l row r: chunk r*4 + ((l>>4)^((r>>1)&3)).
// 0 bank conflicts + intact 64B-line write coalescing.
// MODE0 = bijective XCD chunking; MODE1 = batch->XCD co-location.
// LESSONS (R8/R9/R12/R13/R14/R17/R18 all regressed): the 3-stage kernels sit
// in a narrow optimum (VGPR<=72, high occupancy, counted vmcnt); K=768-class
// panels are too shallow for deeper pipelines -- do not perturb the hot loop.

typedef _Float16 f16x8 __attribute__((ext_vector_type(8)));
typedef _Float16 f16x4 __attribute__((ext_vector_type(4)));
typedef float f32x4 __attribute__((ext_vector_type(4)));

__global__ void cvt8_kernel(const float* __restrict__ src, _Float16* __restrict__ dst,
                            long long n8) {
    long long i = blockIdx.x * (long long)blockDim.x + threadIdx.x;
    const long long stride = gridDim.x * (long long)blockDim.x;
    for (; i < n8; i += stride) {
        const float4 f0 = ((const float4*)src)[2 * i];
        const float4 f1 = ((const float4*)src)[2 * i + 1];
        f16x8 h;
        h[0] = (_Float16)f0.x; h[1] = (_Float16)f0.y; h[2] = (_Float16)f0.z; h[3] = (_Float16)f0.w;
        h[4] = (_Float16)f1.x; h[5] = (_Float16)f1.y; h[6] = (_Float16)f1.z; h[7] = (_Float16)f1.w;
        ((f16x8*)dst)[i] = h;
    }
}

// two f32 [768,768] -> f16 transposed [768,768] (z selects matrix)
__global__ void cvtT2_kernel(const float* __restrict__ s0, _Float16* __restrict__ d0,
                             const float* __restrict__ s1, _Float16* __restrict__ d1) {
    __shared__ float t[32][33];
    const float* src = blockIdx.z ? s1 : s0;
    _Float16* dst = blockIdx.z ? d1 : d0;
    const int bx = blockIdx.x, by = blockIdx.y;
    const int tx = threadIdx.x & 31, ty = threadIdx.x >> 5;
#pragma unroll
    for (int k = 0; k < 4; ++k) {
        const int r = ty + 8 * k;
        t[r][tx] = src[(size_t)(by * 32 + r) * 768 + bx * 32 + tx];
    }
    __syncthreads();
#pragma unroll
    for (int k = 0; k < 4; ++k) {
        const int r = ty + 8 * k;
        dst[(size_t)(bx * 32 + r) * 768 + by * 32 + tx] = (_Float16)t[tx][r];
    }
}

// w1 -> Mt_aug row 768 ; w2f ; bias_mg[1408] ; zero Mt_aug rows 769..799
__global__ void prep_kernel(const _Float16* __restrict__ WqT, const _Float16* __restrict__ WkT,
                            const float* __restrict__ bq, const float* __restrict__ bk,
                            const float* __restrict__ bv,
                            float* __restrict__ w2f, _Float16* __restrict__ Mt_aug,
                            float* __restrict__ bias_mg) {
    const int wid = blockIdx.x * 4 + (threadIdx.x >> 6);
    const int lane = threadIdx.x & 63;
    if (wid < 768) {                 // w1[wid] = WqT[wid,:]·bk
        float s = 0.f;
        for (int k = 0; k < 12; ++k) s += (float)WqT[(size_t)wid * 768 + lane + 64 * k] * bk[lane + 64 * k];
        for (int o = 32; o; o >>= 1) s += __shfl_xor(s, o);
        if (lane == 0) Mt_aug[(size_t)768 * 768 + wid] = (_Float16)s;
    } else if (wid < 1536) {         // w2[n] = WkT[n,:]·bq
        const int n = wid - 768;
        float s = 0.f;
        for (int k = 0; k < 12; ++k) s += (float)WkT[(size_t)n * 768 + lane + 64 * k] * bq[lane + 64 * k];
        for (int o = 32; o; o >>= 1) s += __shfl_xor(s, o);
        if (lane == 0) w2f[n] = s;
    } else if (wid == 1536) {        // c0 -> bias_mg[768], 1 -> [769], 0 -> 770..799
        float s = 0.f;
        for (int k = 0; k < 12; ++k) s += bq[lane + 64 * k] * bk[lane + 64 * k];
        for (int o = 32; o; o >>= 1) s += __shfl_xor(s, o);
        if (lane < 32) {
            float v = 0.f;
            if (lane == 0) v = s;
            if (lane == 1) v = 1.f;
            bias_mg[768 + lane] = v;
        }
    } else if (wid < 1560) {         // bias_mg: zeros 0..767 ; bv -> 800..1376 ; 0 pads
        const int i = (wid - 1537) * 64 + lane;     // [0,1472)
        if (i < 768) bias_mg[i] = 0.f;
        else {
            const int j = i + 32;                   // 800..1503
            if (j < 1408) bias_mg[j] = (j < 1377) ? bv[j - 800] : 0.f;
        }
    } else if (wid < 1591) {         // zero Mt_aug rows 769..799
        const int r = 769 + (wid - 1560);
        for (int k = 0; k < 12; ++k) Mt_aug[(size_t)r * 768 + lane + 64 * k] = (_Float16)0.f;
    }
}

// e f32 [rows,768] -> e' f16 [rows,800]: cvt + col768=1 + col769=e·w2 + 770..799=0
__global__ void cvt_e_aug_kernel(const float* __restrict__ e, const float* __restrict__ w2f,
                                 _Float16* __restrict__ dst, int rows) {
    const int wpb = blockDim.x >> 6;
    int wid = blockIdx.x * wpb + (threadIdx.x >> 6);
    const int nw = gridDim.x * wpb;
    const int lane = threadIdx.x & 63;
    for (int s = wid; s < rows; s += nw) {
        const float4* er = (const float4*)(e + (size_t)s * 768);
        _Float16* dr = dst + (size_t)s * 800;
        float dot = 0.f;
#pragma unroll
        for (int k = 0; k < 3; ++k) {
            const int idx = lane + 64 * k;
            const float4 v = er[idx];
            const float4 w = ((const float4*)w2f)[idx];
            dot += v.x * w.x + v.y * w.y + v.z * w.z + v.w * w.w;
            f16x4 h;
            h[0] = (_Float16)v.x; h[1] = (_Float16)v.y;
            h[2] = (_Float16)v.z; h[3] = (_Float16)v.w;
            *(f16x4*)(dr + 4 * idx) = h;
        }
        for (int o = 32; o; o >>= 1) dot += __shfl_xor(dot, o);
        if (lane < 32) {
            _Float16 v = (_Float16)0.f;
            if (lane == 0) v = (_Float16)1.f;
            if (lane == 1) v = (_Float16)dot;
            dr[768 + lane] = v;
        }
    }
}

__device__ __forceinline__ void gload16(const _Float16* g, _Float16* l) {
    __builtin_amdgcn_global_load_lds(
        (const __attribute__((address_space(1))) unsigned int*)(g),
        (__attribute__((address_space(3))) unsigned int*)(l),
        16, 0, 0);
}

// overflow-safe fast tanh: 1 - 2*rcp(exp2(2log2e*x)+1)
__device__ __forceinline__ float fast_tanh(float x) {
    const float t = __builtin_amdgcn_exp2f(2.885390081777927f * x);
    return 1.f - 2.f * __builtin_amdgcn_rcpf(t + 1.f);
}

// ======== gemm256m: 256x128 (MxN) / BK=32 / 8-wave 3-stage (R16) ===========
// 8 waves (4M x 2N of 64x64); 3 loads/stage/thread -> vmcnt(3); LDS 72 KB.
__global__ __launch_bounds__(512)
void gemm256m(const _Float16* __restrict__ A, const _Float16* __restrict__ Bt,
              const float* __restrict__ bias, _Float16* __restrict__ C,
              int M, int Nreal, int Nstore, int K,
              int lda, int ldb, int ldc, int nTileN)
{
    __shared__ __align__(16) _Float16 lds[3 * 12288];   // 3 x (A 16KB + B 8KB)

    int bid = blockIdx.x;
    {   // bijective XCD chunking (m204)
        const int nwg = gridDim.x;
        const int q8 = nwg >> 3, r8 = nwg & 7;
        const int xcd = bid & 7, loc = bid >> 3;
        bid = (xcd < r8 ? xcd * (q8 + 1) : r8 * (q8 + 1) + (xcd - r8) * q8) + loc;
    }
    const int tm = bid / nTileN, tn = bid - tm * nTileN;
    const int m0 = tm << 8, n0 = tn << 7;

    const int tid = threadIdx.x;
    const int lane = tid & 63;
    const int wid = tid >> 6;
    const int wm = wid >> 1;            // 0..3 M quarter (64 rows)
    const int wn = wid & 1;             // 0..1 N half (64 cols)

    const int r0 = tid >> 2;
    const int c0 = (((tid & 3) ^ ((tid >> 3) & 3)) << 3);
    int ra0 = m0 + r0;        if (ra0 >= M) ra0 = M - 1;
    int ra1 = m0 + 128 + r0;  if (ra1 >= M) ra1 = M - 1;
    int rb0 = n0 + r0;        if (rb0 >= Nreal) rb0 = Nreal - 1;
    const _Float16* pA0 = A + (size_t)ra0 * lda + c0;
    const _Float16* pA1 = A + (size_t)ra1 * lda + c0;
    const _Float16* pB0 = Bt + (size_t)rb0 * ldb + c0;

    const int o0 = tid * 8, o1 = (tid + 512) * 8;

    const int rr = lane & 15;
    const int hh = lane >> 4;
    const int sw = (rr >> 1) & 3;
    const int fAo = ((wm * 64 + rr) * 4 + (hh ^ sw)) * 8;
    const int fBo = ((wn * 64 + rr) * 4 + (hh ^ sw)) * 8;

    const f32x4 z4 = {0.f, 0.f, 0.f, 0.f};
    f32x4 acc[4][4];
#pragma unroll
    for (int i = 0; i < 4; ++i)
#pragma unroll
        for (int j = 0; j < 4; ++j) acc[i][j] = z4;

    const int nt = K >> 5;

#define STAGE(si, kt)                                              \
    do {                                                           \
        _Float16* base_ = lds + (si) * 12288;                      \
        const int ko_ = (kt) << 5;                                 \
        gload16(pA0 + ko_, base_ + o0);                            \
        gload16(pA1 + ko_, base_ + o1);                            \
        gload16(pB0 + ko_, base_ + 8192 + o0);                     \
    } while (0)

#define COMPUTE(si)                                                            \
    do {                                                                       \
        const _Float16* cA_ = lds + (si) * 12288;                              \
        const _Float16* cB_ = cA_ + 8192;                                      \
        f16x8 a_[4], b_[4];                                                    \
        _Pragma("unroll")                                                      \
        for (int mi = 0; mi < 4; ++mi) a_[mi] = *(const f16x8*)(cA_ + fAo + mi * 512); \
        _Pragma("unroll")                                                      \
        for (int ni = 0; ni < 4; ++ni) b_[ni] = *(const f16x8*)(cB_ + fBo + ni * 512); \
        _Pragma("unroll")                                                      \
        for (int mi = 0; mi < 4; ++mi)                                         \
            _Pragma("unroll")                                                  \
            for (int ni = 0; ni < 4; ++ni)                                     \
                acc[mi][ni] = __builtin_amdgcn_mfma_f32_16x16x32_f16(          \
                    a_[mi], b_[ni], acc[mi][ni], 0, 0, 0);                     \
    } while (0)

    STAGE(0, 0);
    STAGE(1, 1);

    for (int j = 0; j < nt - 1; ++j) {
        asm volatile("s_waitcnt vmcnt(3)" ::: "memory");
        __builtin_amdgcn_s_barrier();
        __builtin_amdgcn_sched_barrier(0);
        if (j + 2 < nt) STAGE((j + 2) % 3, j + 2);
        COMPUTE(j % 3);
    }
    asm volatile("s_waitcnt vmcnt(0)" ::: "memory");
    __builtin_amdgcn_s_barrier();
    __builtin_amdgcn_sched_barrier(0);
    COMPUTE((nt - 1) % 3);

#undef STAGE
#undef COMPUTE

    const int cr0 = (lane >> 4) << 2;
    const int cc = lane & 15;
#pragma unroll
    for (int mi = 0; mi < 4; ++mi) {
#pragma unroll
        for (int ni = 0; ni < 4; ++ni) {
            const int gc = n0 + wn * 64 + ni * 16 + cc;
            if (gc >= Nstore) continue;
            const bool real = gc < Nreal;
            const float bb = real ? bias[gc] : 0.f;
#pragma unroll
            for (int r = 0; r < 4; ++r) {
                const int gr = m0 + wm * 64 + mi * 16 + cr0 + r;
                if (gr >= M) continue;
                const float x = real ? (acc[mi][ni][r] + bb) : 0.f;
                C[(size_t)gr * ldc + gc] = (_Float16)x;
            }
        }
    }
}

// -------- 128x128 / BK=32 / 3-stage counted-vmcnt GEMM (R7, proven) ----------
template<bool TANH, bool OUT_F16, bool BIAS, int MODE>
__global__ __launch_bounds__(256)
void gemm_nt_f16(const _Float16* __restrict__ A, const _Float16* __restrict__ Bt,
                 const float* __restrict__ bias, void* __restrict__ Cp,
                 int M, int Nreal, int Nstore, int K,
                 int lda, int ldb, int ldc, int nTileN, int nTiles,
                 long long sA, long long sB, long long sC)
{
    __shared__ __align__(16) _Float16 lds[3 * 8192];

    int bid = blockIdx.x;
    int z, tm, tn;
    if (MODE == 0) {
        const int nwg = gridDim.x;
        const int q8 = nwg >> 3, r8 = nwg & 7;
        const int xcd = bid & 7, loc = bid >> 3;
        bid = (xcd < r8 ? xcd * (q8 + 1) : r8 * (q8 + 1) + (xcd - r8) * q8) + loc;
        z = 0;
        tm = bid / nTileN; tn = bid - tm * nTileN;
    } else {
        const int xcd = bid & 7, idx = bid >> 3;
        const int g = idx / nTiles, tile = idx - g * nTiles;
        z = g * 8 + xcd;
        tm = tile / nTileN; tn = tile - tm * nTileN;
    }
    const int m0 = tm << 7, n0 = tn << 7;

    const _Float16* Az = A + (size_t)z * sA;
    const _Float16* Bz = Bt + (size_t)z * sB;

    const int tid = threadIdx.x;
    const int lane = tid & 63;
    const int wid = tid >> 6;
    const int wm = wid >> 1, wn = wid & 1;

    const int r0 = tid >> 2;
    const int c0 = (((tid & 3) ^ ((tid >> 3) & 3)) << 3);
    const int rA0 = (m0 + r0      < M ? m0 + r0      : M - 1);
    const int rA1 = (m0 + r0 + 64 < M ? m0 + r0 + 64 : M - 1);
    const int rB0 = (n0 + r0      < Nreal ? n0 + r0      : Nreal - 1);
    const int rB1 = (n0 + r0 + 64 < Nreal ? n0 + r0 + 64 : Nreal - 1);
    const _Float16* pA0 = Az + (size_t)rA0 * lda + c0;
    const _Float16* pA1 = Az + (size_t)rA1 * lda + c0;
    const _Float16* pB0 = Bz + (size_t)rB0 * ldb + c0;
    const _Float16* pB1 = Bz + (size_t)rB1 * ldb + c0;

    const int o0 = tid * 8, o1 = (tid + 256) * 8;

    const int rr = lane & 15;
    const int hh = lane >> 4;
    const int sw = (rr >> 1) & 3;
    const int fAo = ((wm * 64 + rr) * 4 + (hh ^ sw)) * 8;
    const int fBo = ((wn * 64 + rr) * 4 + (hh ^ sw)) * 8;

    const f32x4 z4 = {0.f, 0.f, 0.f, 0.f};
    f32x4 acc[4][4];
#pragma unroll
    for (int i = 0; i < 4; ++i)
#pragma unroll
        for (int j = 0; j < 4; ++j) acc[i][j] = z4;

    const int nt = K >> 5;

#define STAGE(si, kt)                                              \
    do {                                                           \
        _Float16* base_ = lds + (si) * 8192;                       \
        const int ko_ = (kt) << 5;                                 \
        gload16(pA0 + ko_, base_ + o0);                            \
        gload16(pA1 + ko_, base_ + o1);                            \
        gload16(pB0 + ko_, base_ + 4096 + o0);                     \
        gload16(pB1 + ko_, base_ + 4096 + o1);                     \
    } while (0)

#define COMPUTE(si)                                                            \
    do {                                                                       \
        const _Float16* cA_ = lds + (si) * 8192;                               \
        const _Float16* cB_ = cA_ + 4096;                                      \
        f16x8 a_[4], b_[4];                                                    \
        _Pragma("unroll")                                                      \
        for (int mi = 0; mi < 4; ++mi) a_[mi] = *(const f16x8*)(cA_ + fAo + mi * 512); \
        _Pragma("unroll")                                                      \
        for (int ni = 0; ni < 4; ++ni) b_[ni] = *(const f16x8*)(cB_ + fBo + ni * 512); \
        _Pragma("unroll")                                                      \
        for (int mi = 0; mi < 4; ++mi)                                         \
            _Pragma("unroll")                                                  \
            for (int ni = 0; ni < 4; ++ni)                                     \
                acc[mi][ni] = __builtin_amdgcn_mfma_f32_16x16x32_f16(          \
                    a_[mi], b_[ni], acc[mi][ni], 0, 0, 0);                     \
    } while (0)

    STAGE(0, 0);
    STAGE(1, 1);

    for (int j = 0; j < nt - 1; ++j) {
        asm volatile("s_waitcnt vmcnt(4)" ::: "memory");
        __builtin_amdgcn_s_barrier();
        __builtin_amdgcn_sched_barrier(0);
        if (j + 2 < nt) STAGE((j + 2) % 3, j + 2);
        COMPUTE(j % 3);
    }
    asm volatile("s_waitcnt vmcnt(0)" ::: "memory");
    __builtin_amdgcn_s_barrier();
    __builtin_amdgcn_sched_barrier(0);
    COMPUTE((nt - 1) % 3);

#undef STAGE
#undef COMPUTE

    const int cr0 = (lane >> 4) << 2;
    const int cc = lane & 15;
    float*    Cf = (float*)Cp    + (size_t)z * sC;
    _Float16* Ch = (_Float16*)Cp + (size_t)z * sC;
#pragma unroll
    for (int mi = 0; mi < 4; ++mi) {
#pragma unroll
        for (int ni = 0; ni < 4; ++ni) {
            const int gc = n0 + wn * 64 + ni * 16 + cc;
            if (gc >= Nstore) continue;
            const bool real = gc < Nreal;
            float bb = 0.f;
            if (BIAS) bb = real ? bias[gc] : 0.f;
#pragma unroll
            for (int r = 0; r < 4; ++r) {
                const int gr = m0 + wm * 64 + mi * 16 + cr0 + r;
                if (gr >= M) continue;
                float x = real ? (acc[mi][ni][r] + bb) : 0.f;
                if (TANH) x = fast_tanh(x);
                if (OUT_F16) Ch[(size_t)gr * ldc + gc] = (_Float16)x;
                else         Cf[(size_t)gr * ldc + gc] = x;
            }
        }
    }
}

extern "C" void kernel_launch(void* const* d_in, const int* in_sizes, int n_in,
                              void* d_out, int out_size, void* d_ws, size_t ws_size,
                              hipStream_t stream)
{
    const float* b  = (const float*)d_in[0];
    const float* e  = (const float*)d_in[1];
    const float* Wq = (const float*)d_in[2];
    const float* bq = (const float*)d_in[3];
    const float* Wk = (const float*)d_in[4];
    const float* bk = (const float*)d_in[5];
    const float* Wv = (const float*)d_in[6];
    const float* bv = (const float*)d_in[7];
    float* out = (float*)d_out;

    const int BT = 36928, T = 577, S = 577, Sp = 608, Kb = 800;
    const int Nmg = 1408;   // merged B rows: 800 aug + 608 v-slot

    // ws layout (f16 units): ~212.5 MB total
    _Float16* WqT_h  = (_Float16*)d_ws;                      // 589824
    _Float16* WkT_h  = WqT_h + 589824;                       // 589824
    _Float16* Mt_aug = WkT_h + 589824;                       // 800*768 (B rows 0..799)
    _Float16* Wv_h   = Mt_aug + 614400;                      // 577*768 (B rows 800..1376)
    float*    bias_mg = (float*)(Wv_h + 443136);             // 1408 f32 (2816 hw)
    float*    w2f     = (float*)((_Float16*)bias_mg + 2816); // 768 f32 (1536 hw)
    _Float16* S1    = (_Float16*)w2f + 1536;                 // b_h [BT,768] then e' [BT,800]
    _Float16* S_big = S1 + (size_t)BT * Kb;                  // [BT,1408]
    _Float16* S4    = S_big + (size_t)BT * Nmg;              // attn [BT,608]

    // weight preprocessing
    cvtT2_kernel<<<dim3(24, 24, 2), 256, 0, stream>>>(Wq, WqT_h, Wk, WkT_h);
    cvt8_kernel<<<217, 256, 0, stream>>>(Wv, Wv_h, 55392);
    prep_kernel<<<398, 256, 0, stream>>>(WqT_h, WkT_h, bq, bk, bv, w2f, Mt_aug, bias_mg);
    // Mt = NT(WkT, WqT)  [768x768] -> Mt_aug rows 0..767
    gemm_nt_f16<false, true, false, 0><<<dim3(36, 1, 1), 256, 0, stream>>>(
        WkT_h, WqT_h, nullptr, Mt_aug, 768, 768, 768, 768, 768, 768, 768, 6, 0, 0, 0, 0);

    // b -> f16
    cvt8_kernel<<<2048, 256, 0, stream>>>(b, S1, 3545088);
    // S_big = b_h @ B_merged^T + bias_mg   [BT,1408]  (145 x 11 tiles of 256x128)
    gemm256m<<<dim3(1595, 1, 1), 512, 0, stream>>>(
        S1, Mt_aug, bias_mg, S_big, BT, 1377, Nmg, 768, 768, 768, Nmg, 11);
    // e' (overwrites b_h, dead)
    cvt_e_aug_kernel<<<2048, 256, 0, stream>>>(e, w2f, S1, BT);
    // attn = tanh(NT(S_big[:,0:800], e'))  batched [64][577,608], K=800
    gemm_nt_f16<true, true, false, 1><<<dim3(1600, 1, 1), 256, 0, stream>>>(
        S_big, S1, nullptr, S4, T, S, Sp, Kb, Nmg, Kb, Sp, 5, 25,
        (long long)T * Nmg, (long long)T * Kb, (long long)T * Sp);
    // out = NT(attn, S_big[:,800:1408])  batched [64][577,577] f32, K=608
    gemm_nt_f16<false, false, false, 1><<<dim3(1600, 1, 1), 256, 0, stream>>>(
        S4, S_big + 800, nullptr, out, T, T, T, Sp, Sp, Nmg, T, 5, 25,
        (long long)T * Sp, (long long)T * Nmg, (long long)T * T);
}